// Round 10
// baseline (139.105 us; speedup 1.0000x reference)
//
#include <hip/hip_runtime.h>
#include <math.h>

#define NN 4096
#define BLK 256
#define SKB 512                         // split-K blocks per matrix
#define NITER (NN * NN / 4 / (SKB * BLK))   // 32 grid-stride steps, exact

typedef float f32x4 __attribute__((ext_vector_type(4)));

// ---------- small helpers ----------

__device__ __forceinline__ float4 ld4(const float* __restrict__ p, int t) {
    return reinterpret_cast<const float4*>(p)[t];
}
__device__ __forceinline__ void st4(float* __restrict__ p, int t, float4 v) {
    reinterpret_cast<float4*>(p)[t] = v;
}
__device__ __forceinline__ float4 add4(float4 a, float4 b) {
    return make_float4(a.x + b.x, a.y + b.y, a.z + b.z, a.w + b.w);
}

// block-wide (sum, sumsq) reduction, blockDim.x == 1024 (16 waves)
__device__ __forceinline__ float2 block_reduce2(float s, float ss, float* sbuf) {
    #pragma unroll
    for (int off = 32; off > 0; off >>= 1) {
        s  += __shfl_down(s,  off, 64);
        ss += __shfl_down(ss, off, 64);
    }
    const int wave = threadIdx.x >> 6;
    const int lane = threadIdx.x & 63;
    if (lane == 0) { sbuf[wave] = s; sbuf[16 + wave] = ss; }
    __syncthreads();
    float rs = 0.f, rss = 0.f;
    if (threadIdx.x < 16) { rs = sbuf[threadIdx.x]; rss = sbuf[16 + threadIdx.x]; }
    if (wave == 0) {
        #pragma unroll
        for (int off = 8; off > 0; off >>= 1) {
            rs  += __shfl_down(rs,  off, 64);
            rss += __shfl_down(rss, off, 64);
        }
        if (lane == 0) { sbuf[0] = rs; sbuf[1] = rss; }
    }
    __syncthreads();
    float2 r = make_float2(sbuf[0], sbuf[1]);
    __syncthreads();
    return r;
}

struct LNStat { float mu, rstd; };

__device__ __forceinline__ LNStat ln_stats(float4 v, float* sbuf) {
    float s  = v.x + v.y + v.z + v.w;
    float ss = v.x * v.x + v.y * v.y + v.z * v.z + v.w * v.w;
    float2 r = block_reduce2(s, ss, sbuf);
    LNStat o;
    o.mu = r.x * (1.0f / NN);
    float var = r.y * (1.0f / NN) - o.mu * o.mu;
    o.rstd = rsqrtf(var + 1e-5f);
    return o;
}

__device__ __forceinline__ float4 ln_apply(float4 v, LNStat st, float4 g, float4 b) {
    return make_float4((v.x - st.mu) * st.rstd * g.x + b.x,
                       (v.y - st.mu) * st.rstd * g.y + b.y,
                       (v.z - st.mu) * st.rstd * g.z + b.z,
                       (v.w - st.mu) * st.rstd * g.w + b.w);
}

__device__ __forceinline__ float4 relu4(float4 v) {
    return make_float4(fmaxf(v.x, 0.f), fmaxf(v.y, 0.f), fmaxf(v.z, 0.f), fmaxf(v.w, 0.f));
}

// ---------- split-K GEMV core: copy-shaped sweep ----------
// Thread t reads float4 index base + s*(SKB*BLK): the whole grid sweeps one
// contiguous 2 MB moving window front-to-back, VGPR loads, no barriers, no
// LDS, unroll 4 (4 loads in flight/thread). All 64 lanes of a wave fall in
// one row (64*4=256 <= 4096), so a wave shuffle-reduce yields one partial
// per wave-iter -> one atomicAdd into y[row]. y must be pre-zeroed.
// NT=1 streams W past L2/LLC (stage A); NT=0 cached (L3-resident B/C).

template<int NT>
__device__ __forceinline__ void splitk_core(const float* __restrict__ W,
                                            const float* __restrict__ x,
                                            const float* __restrict__ xa,
                                            float* __restrict__ y) {
    const f32x4*  W4 = reinterpret_cast<const f32x4*>(W);
    const float4* x4 = reinterpret_cast<const float4*>(x);
    const float4* a4 = reinterpret_cast<const float4*>(xa);
    const int lane = threadIdx.x & 63;
    const int base = blockIdx.x * BLK + threadIdx.x;
    #pragma unroll 4
    for (int s = 0; s < NITER; ++s) {
        const int i = base + s * (SKB * BLK);
        f32x4 w;
        if (NT) w = __builtin_nontemporal_load(W4 + i);
        else    w = W4[i];
        const int c = i & (NN / 4 - 1);
        float4 xv = x4[c];
        if (xa) xv = add4(xv, a4[c]);
        float p = fmaf(w.x, xv.x, fmaf(w.y, xv.y, fmaf(w.z, xv.z, w.w * xv.w)));
        #pragma unroll
        for (int off = 32; off > 0; off >>= 1) p += __shfl_down(p, off, 64);
        if (lane == 0) atomicAdd(y + (i >> 10), p);
    }
}

// Stage A: mv1 = W_H1_H1 @ h1_prev; mv2 = W_H2_H2 @ h2_prev; mv3 = W_I_H1 @ (input_raw + b_i)
__global__ __launch_bounds__(BLK) void gemv_stageA(
    const float* __restrict__ W_H1_H1, const float* __restrict__ h1_prev,
    const float* __restrict__ W_H2_H2, const float* __restrict__ h2_prev,
    const float* __restrict__ W_I_H1,  const float* __restrict__ input_raw,
    const float* __restrict__ b_i,
    float* __restrict__ mv1, float* __restrict__ mv2, float* __restrict__ mv3)
{
    const float* W; const float* x; const float* xa; float* y;
    if (blockIdx.y == 0)      { W = W_H1_H1; x = h1_prev;   xa = nullptr; y = mv1; }
    else if (blockIdx.y == 1) { W = W_H2_H2; x = h2_prev;   xa = nullptr; y = mv2; }
    else                      { W = W_I_H1;  x = input_raw; xa = b_i;     y = mv3; }
    splitk_core<1>(W, x, xa, y);   // NT: don't evict L3-resident B/C weights
}

// Pair of independent GEMVs (stages B and C) — cached (L3-resident)
__global__ __launch_bounds__(BLK) void gemv_pair(
    const float* __restrict__ Wa, const float* __restrict__ xva, float* __restrict__ ya,
    const float* __restrict__ Wb, const float* __restrict__ xvb, float* __restrict__ yb)
{
    const float* W; const float* x; float* y;
    if (blockIdx.y == 0) { W = Wa; x = xva; y = ya; }
    else                 { W = Wb; x = xvb; y = yb; }
    splitk_core<0>(W, x, nullptr, y);
}

// ---------- Phase 2: two independent LN chains, one block each ----------
__global__ __launch_bounds__(1024) void phase2_kernel(
    const float* __restrict__ mv1, const float* __restrict__ mv2, const float* __restrict__ mv3,
    const float* __restrict__ bias_h1, const float* __restrict__ bias_h2,
    const float* __restrict__ g_h1, const float* __restrict__ bln_h1,
    const float* __restrict__ g_h2, const float* __restrict__ bln_h2,
    float* __restrict__ h1_p2, float* __restrict__ h2_p2)
{
    __shared__ float sbuf[32];
    const int t = threadIdx.x;
    if (blockIdx.x == 0) {
        float4 g = ld4(g_h1, t), b = ld4(bln_h1, t);
        float4 v = ld4(mv1, t);
        LNStat s1 = ln_stats(v, sbuf);
        float4 fb = ln_apply(v, s1, g, b);
        float4 tt = add4(add4(ld4(mv3, t), fb), ld4(bias_h1, t));
        LNStat s2 = ln_stats(tt, sbuf);
        st4(h1_p2, t, relu4(ln_apply(tt, s2, g, b)));
    } else {
        float4 g = ld4(g_h2, t), b = ld4(bln_h2, t);
        float4 v = ld4(mv2, t);
        LNStat s1 = ln_stats(v, sbuf);
        float4 fb = ln_apply(v, s1, g, b);
        float4 tt = add4(fb, ld4(bias_h2, t));
        LNStat s2 = ln_stats(tt, sbuf);
        st4(h2_p2, t, relu4(ln_apply(tt, s2, g, b)));
    }
}

// ---------- Phase 3 norms: two independent LNs, one block each ----------
__global__ __launch_bounds__(1024) void phase3_kernel(
    const float* __restrict__ mv4, const float* __restrict__ mv5,
    const float* __restrict__ bias_h1, const float* __restrict__ bias_h2,
    const float* __restrict__ g_h1, const float* __restrict__ bln_h1,
    const float* __restrict__ g_h2, const float* __restrict__ bln_h2,
    float* __restrict__ h1_f, float* __restrict__ h2_f)
{
    __shared__ float sbuf[32];
    const int t = threadIdx.x;
    const float* mv;  const float* bias; const float* g; const float* b; float* out;
    if (blockIdx.x == 0) { mv = mv4; bias = bias_h1; g = g_h1; b = bln_h1; out = h1_f; }
    else                 { mv = mv5; bias = bias_h2; g = g_h2; b = bln_h2; out = h2_f; }
    float4 v = add4(ld4(mv, t), ld4(bias, t));
    LNStat s = ln_stats(v, sbuf);
    st4(out, t, relu4(ln_apply(v, s, ld4(g, t), ld4(b, t))));
}

// ---------- Final: o = tanh(LN(bln_o + mv6 + mv7 + bias_o, g_o, bln_o)) ----------
__global__ __launch_bounds__(1024) void final_kernel(
    const float* __restrict__ mv6, const float* __restrict__ mv7,
    const float* __restrict__ bias_o, const float* __restrict__ bln_o,
    const float* __restrict__ g_o,
    float* __restrict__ out)
{
    __shared__ float sbuf[32];
    const int t = threadIdx.x;
    float4 v = add4(add4(ld4(bln_o, t), ld4(mv6, t)), add4(ld4(mv7, t), ld4(bias_o, t)));
    LNStat s = ln_stats(v, sbuf);
    float4 r = ln_apply(v, s, ld4(g_o, t), ld4(bln_o, t));
    st4(out, t, make_float4(tanhf(r.x), tanhf(r.y), tanhf(r.z), tanhf(r.w)));
}

// ---------- launch ----------

extern "C" void kernel_launch(void* const* d_in, const int* in_sizes, int n_in,
                              void* d_out, int out_size, void* d_ws, size_t ws_size,
                              hipStream_t stream) {
    const float* input_raw = (const float*)d_in[0];
    const float* h1_prev   = (const float*)d_in[1];
    const float* h2_prev   = (const float*)d_in[2];
    const float* W_I_H1    = (const float*)d_in[3];
    const float* W_H1_H1   = (const float*)d_in[4];
    const float* W_H1_H2   = (const float*)d_in[5];
    const float* W_H2_H1   = (const float*)d_in[6];
    const float* W_H2_H2   = (const float*)d_in[7];
    const float* W_H1_O    = (const float*)d_in[8];
    const float* W_H2_O    = (const float*)d_in[9];
    const float* bias_h1   = (const float*)d_in[10];
    const float* bias_h2   = (const float*)d_in[11];
    const float* bias_o    = (const float*)d_in[12];
    // d_in[13] = g_i (unused: LN(zeros) == beta)
    const float* b_i       = (const float*)d_in[14];
    const float* g_h1      = (const float*)d_in[15];
    const float* bln_h1    = (const float*)d_in[16];
    const float* g_h2      = (const float*)d_in[17];
    const float* bln_h2    = (const float*)d_in[18];
    const float* g_o       = (const float*)d_in[19];
    const float* bln_o     = (const float*)d_in[20];

    float* ws    = (float*)d_ws;
    float* mv1   = ws;
    float* mv2   = ws + 1 * NN;
    float* mv3   = ws + 2 * NN;
    float* h1_p2 = ws + 3 * NN;
    float* h2_p2 = ws + 4 * NN;
    float* mv4   = ws + 5 * NN;
    float* mv5   = ws + 6 * NN;
    float* h1_f  = ws + 7 * NN;
    float* h2_f  = ws + 8 * NN;
    float* mv6   = ws + 9 * NN;
    float* mv7   = ws + 10 * NN;

    // zero the accumulator buffers (atomic split-K accumulates into them)
    hipMemsetAsync(ws, 0, 11 * NN * sizeof(float), stream);

    // Stage A: 3 independent GEMVs (NT weight streaming, split-K copy-shape)
    gemv_stageA<<<dim3(SKB, 3), BLK, 0, stream>>>(
        W_H1_H1, h1_prev, W_H2_H2, h2_prev, W_I_H1, input_raw, b_i, mv1, mv2, mv3);

    // Phase 2 LN chains
    phase2_kernel<<<2, 1024, 0, stream>>>(
        mv1, mv2, mv3, bias_h1, bias_h2, g_h1, bln_h1, g_h2, bln_h2, h1_p2, h2_p2);

    // Stage B: mv4 = W_H2_H1 @ h2_p2 ; mv5 = W_H1_H2 @ h1_p2
    gemv_pair<<<dim3(SKB, 2), BLK, 0, stream>>>(
        W_H2_H1, h2_p2, mv4, W_H1_H2, h1_p2, mv5);

    // Phase 3 norms
    phase3_kernel<<<2, 1024, 0, stream>>>(
        mv4, mv5, bias_h1, bias_h2, g_h1, bln_h1, g_h2, bln_h2, h1_f, h2_f);

    // Stage C: mv6 = W_H1_O @ h1_f ; mv7 = W_H2_O @ h2_f
    gemv_pair<<<dim3(SKB, 2), BLK, 0, stream>>>(
        W_H1_O, h1_f, mv6, W_H2_O, h2_f, mv7);

    // Final output
    final_kernel<<<1, 1024, 0, stream>>>(
        mv6, mv7, bias_o, bln_o, g_o, (float*)d_out);
}

// Round 11
// 92.885 us; speedup vs baseline: 1.4976x; 1.4976x over previous
//
#include <hip/hip_runtime.h>
#include <math.h>

#define NN 4096
#define GX 256              // blocks per matrix; block b owns rows {b + j*GX}
#define NROWS 16
#define BLK 256

// ---------- small helpers ----------

__device__ __forceinline__ float4 ld4(const float* __restrict__ p, int t) {
    return reinterpret_cast<const float4*>(p)[t];
}
__device__ __forceinline__ void st4(float* __restrict__ p, int t, float4 v) {
    reinterpret_cast<float4*>(p)[t] = v;
}
__device__ __forceinline__ float4 add4(float4 a, float4 b) {
    return make_float4(a.x + b.x, a.y + b.y, a.z + b.z, a.w + b.w);
}

// async global->LDS, 16B per lane; LDS dst is wave-uniform base (+lane*16 implicit)
// AUX cache policy: 0 = normal, 2 = NT (non-temporal; no L2/LLC retention).
typedef const __attribute__((address_space(1))) unsigned int* gas1_u32;
typedef __attribute__((address_space(3))) unsigned int* las3_u32;
template<int AUX>
__device__ __forceinline__ void async16(const float* g, float* l) {
    __builtin_amdgcn_global_load_lds((gas1_u32)(const void*)g, (las3_u32)(void*)l, 16, 0, AUX);
}

// stage one full 16 KB row into LDS: wave w covers bytes [4w,4w+4) KB (4 loads/wave)
template<int AUX>
__device__ __forceinline__ void stage_row(const float* __restrict__ W, int row,
                                          float* __restrict__ buf, int wave, int lane) {
    const float* g = W + (size_t)row * NN + wave * 1024 + lane * 4;
    float* l = buf + wave * 1024;
    async16<AUX>(g,       l);
    async16<AUX>(g + 256, l + 256);
    async16<AUX>(g + 512, l + 512);
    async16<AUX>(g + 768, l + 768);
}

// dot(row-in-LDS, x-in-regs) -> wave-reduced partial (valid in lane 0)
__device__ __forceinline__ float dot_row(const float* __restrict__ buf,
                                         const float4 xr[4], int tid) {
    const float4* b4 = reinterpret_cast<const float4*>(buf);
    float p = 0.f;
    #pragma unroll
    for (int i = 0; i < 4; ++i) {
        float4 w = b4[i * 256 + tid];
        p = fmaf(w.x, xr[i].x, p);
        p = fmaf(w.y, xr[i].y, p);
        p = fmaf(w.z, xr[i].z, p);
        p = fmaf(w.w, xr[i].w, p);
    }
    #pragma unroll
    for (int off = 32; off > 0; off >>= 1) p += __shfl_down(p, off, 64);
    return p;
}

// block-wide (sum, sumsq) reduction, blockDim.x == 1024 (16 waves)
__device__ __forceinline__ float2 block_reduce2(float s, float ss, float* sbuf) {
    #pragma unroll
    for (int off = 32; off > 0; off >>= 1) {
        s  += __shfl_down(s,  off, 64);
        ss += __shfl_down(ss, off, 64);
    }
    const int wave = threadIdx.x >> 6;
    const int lane = threadIdx.x & 63;
    if (lane == 0) { sbuf[wave] = s; sbuf[16 + wave] = ss; }
    __syncthreads();
    float rs = 0.f, rss = 0.f;
    if (threadIdx.x < 16) { rs = sbuf[threadIdx.x]; rss = sbuf[16 + threadIdx.x]; }
    if (wave == 0) {
        #pragma unroll
        for (int off = 8; off > 0; off >>= 1) {
            rs  += __shfl_down(rs,  off, 64);
            rss += __shfl_down(rss, off, 64);
        }
        if (lane == 0) { sbuf[0] = rs; sbuf[1] = rss; }
    }
    __syncthreads();
    float2 r = make_float2(sbuf[0], sbuf[1]);
    __syncthreads();
    return r;
}

struct LNStat { float mu, rstd; };

__device__ __forceinline__ LNStat ln_stats(float4 v, float* sbuf) {
    float s  = v.x + v.y + v.z + v.w;
    float ss = v.x * v.x + v.y * v.y + v.z * v.z + v.w * v.w;
    float2 r = block_reduce2(s, ss, sbuf);
    LNStat o;
    o.mu = r.x * (1.0f / NN);
    float var = r.y * (1.0f / NN) - o.mu * o.mu;
    o.rstd = rsqrtf(var + 1e-5f);
    return o;
}

__device__ __forceinline__ float4 ln_apply(float4 v, LNStat st, float4 g, float4 b) {
    return make_float4((v.x - st.mu) * st.rstd * g.x + b.x,
                       (v.y - st.mu) * st.rstd * g.y + b.y,
                       (v.z - st.mu) * st.rstd * g.z + b.z,
                       (v.w - st.mu) * st.rstd * g.w + b.w);
}

__device__ __forceinline__ float4 relu4(float4 v) {
    return make_float4(fmaxf(v.x, 0.f), fmaxf(v.y, 0.f), fmaxf(v.z, 0.f), fmaxf(v.w, 0.f));
}

// ---------- GEMV core: moving-window sweep + counted-vmcnt pipeline ----------
// Block b owns rows {b + j*GX} (chip-wide contiguous 4 MB window per step).
// 3 LDS row-buffers, 2 rows staged ahead. Per phase: stage row j+2, compute
// row j, then s_waitcnt vmcnt(4) (row j+1 complete; row j+2's 4 loads REMAIN
// IN FLIGHT across the barrier) + raw s_barrier. Never drains to 0 mid-loop.
// y-results accumulate in LDS (no global stores inside the vmcnt stream).

template<int AUX>
__device__ __forceinline__ void gemv_core(const float* __restrict__ W,
                                          const float* __restrict__ x,
                                          const float* __restrict__ xadd,
                                          float* __restrict__ y,
                                          float* tiles, float* sbuf, float* ys) {
    const int tid  = threadIdx.x;
    const int wave = tid >> 6;
    const int lane = tid & 63;
    const int r0 = blockIdx.x;          // rows r0 + j*GX

    // x into registers FIRST, then drain, so stage loads are the only vmcnt ops
    float4 xr[4];
    const float4* x4 = reinterpret_cast<const float4*>(x);
    #pragma unroll
    for (int i = 0; i < 4; ++i) xr[i] = x4[i * 256 + tid];
    if (xadd) {
        const float4* a4 = reinterpret_cast<const float4*>(xadd);
        #pragma unroll
        for (int i = 0; i < 4; ++i) xr[i] = add4(xr[i], a4[i * 256 + tid]);
    }
    asm volatile("s_waitcnt vmcnt(0)" ::: "memory");

    // prologue: stage rows 0,1; wait row 0 (row 1 stays in flight)
    stage_row<AUX>(W, r0 + 0 * GX, tiles + 0 * NN, wave, lane);
    stage_row<AUX>(W, r0 + 1 * GX, tiles + 1 * NN, wave, lane);
    asm volatile("s_waitcnt vmcnt(4)" ::: "memory");
    __builtin_amdgcn_sched_barrier(0);
    __builtin_amdgcn_s_barrier();

    #pragma unroll
    for (int j = 0; j < NROWS; ++j) {
        if (tid == 0 && j > 0) {
            const int pp = ((j - 1) & 1) * 4;
            ys[j - 1] = sbuf[pp] + sbuf[pp + 1] + sbuf[pp + 2] + sbuf[pp + 3];
        }
        if (j + 2 < NROWS)
            stage_row<AUX>(W, r0 + (j + 2) * GX, tiles + ((j + 2) % 3) * NN, wave, lane);
        float p = dot_row(tiles + (j % 3) * NN, xr, tid);
        if (lane == 0) sbuf[(j & 1) * 4 + wave] = p;
        if (j <= NROWS - 3)
            asm volatile("s_waitcnt vmcnt(4) lgkmcnt(0)" ::: "memory");
        else
            asm volatile("s_waitcnt vmcnt(0) lgkmcnt(0)" ::: "memory");
        __builtin_amdgcn_sched_barrier(0);
        __builtin_amdgcn_s_barrier();
    }
    if (tid == 0) {
        const int pp = ((NROWS - 1) & 1) * 4;
        ys[NROWS - 1] = sbuf[pp] + sbuf[pp + 1] + sbuf[pp + 2] + sbuf[pp + 3];
    }
    __syncthreads();
    if (tid < NROWS) y[r0 + tid * GX] = ys[tid];
}

// Stage A: mv1 = W_H1_H1 @ h1_prev; mv2 = W_H2_H2 @ h2_prev; mv3 = W_I_H1 @ (input_raw + b_i)
// NT streaming: 192 MB pass through without evicting the L3-resident B/C weights.
__global__ __launch_bounds__(BLK) void gemv_stageA(
    const float* __restrict__ W_H1_H1, const float* __restrict__ h1_prev,
    const float* __restrict__ W_H2_H2, const float* __restrict__ h2_prev,
    const float* __restrict__ W_I_H1,  const float* __restrict__ input_raw,
    const float* __restrict__ b_i,
    float* __restrict__ mv1, float* __restrict__ mv2, float* __restrict__ mv3)
{
    __shared__ float tiles[3 * NN];    // 48 KB: 3 row buffers
    __shared__ float sbuf[8];
    __shared__ float ys[NROWS];
    const float* W; const float* x; const float* xadd; float* y;
    if (blockIdx.y == 0)      { W = W_H1_H1; x = h1_prev;   xadd = nullptr; y = mv1; }
    else if (blockIdx.y == 1) { W = W_H2_H2; x = h2_prev;   xadd = nullptr; y = mv2; }
    else                      { W = W_I_H1;  x = input_raw; xadd = b_i;     y = mv3; }
    gemv_core<2>(W, x, xadd, y, tiles, sbuf, ys);   // AUX=2 -> NT
}

// Pair of independent GEMVs (stages B and C) — default caching (L3-resident)
__global__ __launch_bounds__(BLK) void gemv_pair(
    const float* __restrict__ Wa, const float* __restrict__ xa, float* __restrict__ ya,
    const float* __restrict__ Wb, const float* __restrict__ xb, float* __restrict__ yb)
{
    __shared__ float tiles[3 * NN];
    __shared__ float sbuf[8];
    __shared__ float ys[NROWS];
    const float* W; const float* x; float* y;
    if (blockIdx.y == 0) { W = Wa; x = xa; y = ya; }
    else                 { W = Wb; x = xb; y = yb; }
    gemv_core<0>(W, x, nullptr, y, tiles, sbuf, ys);
}

// ---------- Phase 2: two independent LN chains, one block each ----------
__global__ __launch_bounds__(1024) void phase2_kernel(
    const float* __restrict__ mv1, const float* __restrict__ mv2, const float* __restrict__ mv3,
    const float* __restrict__ bias_h1, const float* __restrict__ bias_h2,
    const float* __restrict__ g_h1, const float* __restrict__ bln_h1,
    const float* __restrict__ g_h2, const float* __restrict__ bln_h2,
    float* __restrict__ h1_p2, float* __restrict__ h2_p2)
{
    __shared__ float sbuf[32];
    const int t = threadIdx.x;
    if (blockIdx.x == 0) {
        float4 g = ld4(g_h1, t), b = ld4(bln_h1, t);
        float4 v = ld4(mv1, t);
        LNStat s1 = ln_stats(v, sbuf);
        float4 fb = ln_apply(v, s1, g, b);
        float4 tt = add4(add4(ld4(mv3, t), fb), ld4(bias_h1, t));
        LNStat s2 = ln_stats(tt, sbuf);
        st4(h1_p2, t, relu4(ln_apply(tt, s2, g, b)));
    } else {
        float4 g = ld4(g_h2, t), b = ld4(bln_h2, t);
        float4 v = ld4(mv2, t);
        LNStat s1 = ln_stats(v, sbuf);
        float4 fb = ln_apply(v, s1, g, b);
        float4 tt = add4(fb, ld4(bias_h2, t));
        LNStat s2 = ln_stats(tt, sbuf);
        st4(h2_p2, t, relu4(ln_apply(tt, s2, g, b)));
    }
}

// ---------- Phase 3 norms: two independent LNs, one block each ----------
__global__ __launch_bounds__(1024) void phase3_kernel(
    const float* __restrict__ mv4, const float* __restrict__ mv5,
    const float* __restrict__ bias_h1, const float* __restrict__ bias_h2,
    const float* __restrict__ g_h1, const float* __restrict__ bln_h1,
    const float* __restrict__ g_h2, const float* __restrict__ bln_h2,
    float* __restrict__ h1_f, float* __restrict__ h2_f)
{
    __shared__ float sbuf[32];
    const int t = threadIdx.x;
    const float* mv;  const float* bias; const float* g; const float* b; float* out;
    if (blockIdx.x == 0) { mv = mv4; bias = bias_h1; g = g_h1; b = bln_h1; out = h1_f; }
    else                 { mv = mv5; bias = bias_h2; g = g_h2; b = bln_h2; out = h2_f; }
    float4 v = add4(ld4(mv, t), ld4(bias, t));
    LNStat s = ln_stats(v, sbuf);
    st4(out, t, relu4(ln_apply(v, s, ld4(g, t), ld4(b, t))));
}

// ---------- Final: o = tanh(LN(bln_o + mv6 + mv7 + bias_o, g_o, bln_o)) ----------
__global__ __launch_bounds__(1024) void final_kernel(
    const float* __restrict__ mv6, const float* __restrict__ mv7,
    const float* __restrict__ bias_o, const float* __restrict__ bln_o,
    const float* __restrict__ g_o,
    float* __restrict__ out)
{
    __shared__ float sbuf[32];
    const int t = threadIdx.x;
    float4 v = add4(add4(ld4(bln_o, t), ld4(mv6, t)), add4(ld4(mv7, t), ld4(bias_o, t)));
    LNStat s = ln_stats(v, sbuf);
    float4 r = ln_apply(v, s, ld4(g_o, t), ld4(bln_o, t));
    st4(out, t, make_float4(tanhf(r.x), tanhf(r.y), tanhf(r.z), tanhf(r.w)));
}

// ---------- launch ----------

extern "C" void kernel_launch(void* const* d_in, const int* in_sizes, int n_in,
                              void* d_out, int out_size, void* d_ws, size_t ws_size,
                              hipStream_t stream) {
    const float* input_raw = (const float*)d_in[0];
    const float* h1_prev   = (const float*)d_in[1];
    const float* h2_prev   = (const float*)d_in[2];
    const float* W_I_H1    = (const float*)d_in[3];
    const float* W_H1_H1   = (const float*)d_in[4];
    const float* W_H1_H2   = (const float*)d_in[5];
    const float* W_H2_H1   = (const float*)d_in[6];
    const float* W_H2_H2   = (const float*)d_in[7];
    const float* W_H1_O    = (const float*)d_in[8];
    const float* W_H2_O    = (const float*)d_in[9];
    const float* bias_h1   = (const float*)d_in[10];
    const float* bias_h2   = (const float*)d_in[11];
    const float* bias_o    = (const float*)d_in[12];
    // d_in[13] = g_i (unused: LN(zeros) == beta)
    const float* b_i       = (const float*)d_in[14];
    const float* g_h1      = (const float*)d_in[15];
    const float* bln_h1    = (const float*)d_in[16];
    const float* g_h2      = (const float*)d_in[17];
    const float* bln_h2    = (const float*)d_in[18];
    const float* g_o       = (const float*)d_in[19];
    const float* bln_o     = (const float*)d_in[20];

    float* ws    = (float*)d_ws;
    float* mv1   = ws;
    float* mv2   = ws + 1 * NN;
    float* mv3   = ws + 2 * NN;
    float* h1_p2 = ws + 3 * NN;
    float* h2_p2 = ws + 4 * NN;
    float* mv4   = ws + 5 * NN;
    float* mv5   = ws + 6 * NN;
    float* h1_f  = ws + 7 * NN;
    float* h2_f  = ws + 8 * NN;
    float* mv6   = ws + 9 * NN;
    float* mv7   = ws + 10 * NN;

    // Stage A: 3 independent GEMVs (NT streaming, moving window, counted-vmcnt pipeline)
    gemv_stageA<<<dim3(GX, 3), BLK, 0, stream>>>(
        W_H1_H1, h1_prev, W_H2_H2, h2_prev, W_I_H1, input_raw, b_i, mv1, mv2, mv3);

    // Phase 2 LN chains
    phase2_kernel<<<2, 1024, 0, stream>>>(
        mv1, mv2, mv3, bias_h1, bias_h2, g_h1, bln_h1, g_h2, bln_h2, h1_p2, h2_p2);

    // Stage B: mv4 = W_H2_H1 @ h2_p2 ; mv5 = W_H1_H2 @ h1_p2
    gemv_pair<<<dim3(GX, 2), BLK, 0, stream>>>(
        W_H2_H1, h2_p2, mv4, W_H1_H2, h1_p2, mv5);

    // Phase 3 norms
    phase3_kernel<<<2, 1024, 0, stream>>>(
        mv4, mv5, bias_h1, bias_h2, g_h1, bln_h1, g_h2, bln_h2, h1_f, h2_f);

    // Stage C: mv6 = W_H1_O @ h1_f ; mv7 = W_H2_O @ h2_f
    gemv_pair<<<dim3(GX, 2), BLK, 0, stream>>>(
        W_H1_O, h1_f, mv6, W_H2_O, h2_f, mv7);

    // Final output
    final_kernel<<<1, 1024, 0, stream>>>(
        mv6, mv7, bias_o, bln_o, g_o, (float*)d_out);
}

// Round 12
// 92.861 us; speedup vs baseline: 1.4980x; 1.0003x over previous
//
#include <hip/hip_runtime.h>
#include <math.h>

#define NN 4096
#define GXW 256             // blocks per matrix (4 waves each -> 1024 waves)
#define BLK 256

typedef float f32x4 __attribute__((ext_vector_type(4)));

// ---------- small helpers ----------

__device__ __forceinline__ float4 ld4(const float* __restrict__ p, int t) {
    return reinterpret_cast<const float4*>(p)[t];
}
__device__ __forceinline__ void st4(float* __restrict__ p, int t, float4 v) {
    reinterpret_cast<float4*>(p)[t] = v;
}
__device__ __forceinline__ float4 add4(float4 a, float4 b) {
    return make_float4(a.x + b.x, a.y + b.y, a.z + b.z, a.w + b.w);
}

// block-wide (sum, sumsq) reduction, blockDim.x == 1024 (16 waves)
__device__ __forceinline__ float2 block_reduce2(float s, float ss, float* sbuf) {
    #pragma unroll
    for (int off = 32; off > 0; off >>= 1) {
        s  += __shfl_down(s,  off, 64);
        ss += __shfl_down(ss, off, 64);
    }
    const int wave = threadIdx.x >> 6;
    const int lane = threadIdx.x & 63;
    if (lane == 0) { sbuf[wave] = s; sbuf[16 + wave] = ss; }
    __syncthreads();
    float rs = 0.f, rss = 0.f;
    if (threadIdx.x < 16) { rs = sbuf[threadIdx.x]; rss = sbuf[16 + threadIdx.x]; }
    if (wave == 0) {
        #pragma unroll
        for (int off = 8; off > 0; off >>= 1) {
            rs  += __shfl_down(rs,  off, 64);
            rss += __shfl_down(rss, off, 64);
        }
        if (lane == 0) { sbuf[0] = rs; sbuf[1] = rss; }
    }
    __syncthreads();
    float2 r = make_float2(sbuf[0], sbuf[1]);
    __syncthreads();
    return r;
}

struct LNStat { float mu, rstd; };

__device__ __forceinline__ LNStat ln_stats(float4 v, float* sbuf) {
    float s  = v.x + v.y + v.z + v.w;
    float ss = v.x * v.x + v.y * v.y + v.z * v.z + v.w * v.w;
    float2 r = block_reduce2(s, ss, sbuf);
    LNStat o;
    o.mu = r.x * (1.0f / NN);
    float var = r.y * (1.0f / NN) - o.mu * o.mu;
    o.rstd = rsqrtf(var + 1e-5f);
    return o;
}

__device__ __forceinline__ float4 ln_apply(float4 v, LNStat st, float4 g, float4 b) {
    return make_float4((v.x - st.mu) * st.rstd * g.x + b.x,
                       (v.y - st.mu) * st.rstd * g.y + b.y,
                       (v.z - st.mu) * st.rstd * g.z + b.z,
                       (v.w - st.mu) * st.rstd * g.w + b.w);
}

__device__ __forceinline__ float4 relu4(float4 v) {
    return make_float4(fmaxf(v.x, 0.f), fmaxf(v.y, 0.f), fmaxf(v.z, 0.f), fmaxf(v.w, 0.f));
}

// ---------- GEMV core: one wave per row, register-windowed stream ----------
// Copy-shaped consumer: no LDS, no barriers, no cross-lane ops in the sweep.
// x lives in 16 float4 regs (loaded once, reused for 4 rows). Weights stream
// through an 8-deep rotating register window w[k&7] (all static indices):
// refill-after-consume gives the compiler a natural counted-vmcnt pipeline,
// 8 KB in flight per wave, ~128 KB per CU. 4 independent FMA chains via
// component-wise f32x4 accumulation. One shuffle-reduce + store per row.
// Moving window: wave g handles rows {g + j*1024} -> chip-wide 16 MB window.

template<int NT>
__device__ __forceinline__ void gemv_wave(const float* __restrict__ W,
                                          const float* __restrict__ x,
                                          const float* __restrict__ xadd,
                                          float* __restrict__ y) {
    const int lane = threadIdx.x & 63;
    const int gwave = blockIdx.x * 4 + (threadIdx.x >> 6);   // 0..1023

    f32x4 xr[16];
    const f32x4* x4 = reinterpret_cast<const f32x4*>(x);
    #pragma unroll
    for (int k = 0; k < 16; ++k) xr[k] = x4[k * 64 + lane];
    if (xadd) {
        const f32x4* a4 = reinterpret_cast<const f32x4*>(xadd);
        #pragma unroll
        for (int k = 0; k < 16; ++k) xr[k] += a4[k * 64 + lane];
    }

    #pragma unroll 1
    for (int j = 0; j < NN / 1024; ++j) {
        const int row = gwave + j * 1024;
        const f32x4* __restrict__ Wr =
            reinterpret_cast<const f32x4*>(W) + (size_t)row * (NN / 4) + lane;
        f32x4 w[8];
        #pragma unroll
        for (int k = 0; k < 8; ++k)
            w[k] = NT ? __builtin_nontemporal_load(Wr + k * 64) : Wr[k * 64];
        f32x4 acc = {0.f, 0.f, 0.f, 0.f};
        #pragma unroll
        for (int k = 0; k < 16; ++k) {
            f32x4 ww = w[k & 7];
            if (k + 8 < 16)
                w[k & 7] = NT ? __builtin_nontemporal_load(Wr + (k + 8) * 64)
                              : Wr[(k + 8) * 64];
            acc.x = fmaf(ww.x, xr[k].x, acc.x);
            acc.y = fmaf(ww.y, xr[k].y, acc.y);
            acc.z = fmaf(ww.z, xr[k].z, acc.z);
            acc.w = fmaf(ww.w, xr[k].w, acc.w);
        }
        float p = (acc.x + acc.y) + (acc.z + acc.w);
        #pragma unroll
        for (int off = 32; off > 0; off >>= 1) p += __shfl_down(p, off, 64);
        if (lane == 0) y[row] = p;
    }
}

// Stage A: mv1 = W_H1_H1 @ h1_prev; mv2 = W_H2_H2 @ h2_prev; mv3 = W_I_H1 @ (input_raw + b_i)
// NT: the 192 MB stream passes through without evicting L3-resident B/C weights.
__global__ __launch_bounds__(BLK) void gemv_stageA(
    const float* __restrict__ W_H1_H1, const float* __restrict__ h1_prev,
    const float* __restrict__ W_H2_H2, const float* __restrict__ h2_prev,
    const float* __restrict__ W_I_H1,  const float* __restrict__ input_raw,
    const float* __restrict__ b_i,
    float* __restrict__ mv1, float* __restrict__ mv2, float* __restrict__ mv3)
{
    const float* W; const float* x; const float* xa; float* y;
    if (blockIdx.y == 0)      { W = W_H1_H1; x = h1_prev;   xa = nullptr; y = mv1; }
    else if (blockIdx.y == 1) { W = W_H2_H2; x = h2_prev;   xa = nullptr; y = mv2; }
    else                      { W = W_I_H1;  x = input_raw; xa = b_i;     y = mv3; }
    gemv_wave<1>(W, x, xa, y);
}

// Pair of independent GEMVs (stages B and C) — cached (L3-resident)
__global__ __launch_bounds__(BLK) void gemv_pair(
    const float* __restrict__ Wa, const float* __restrict__ xva, float* __restrict__ ya,
    const float* __restrict__ Wb, const float* __restrict__ xvb, float* __restrict__ yb)
{
    const float* W; const float* x; float* y;
    if (blockIdx.y == 0) { W = Wa; x = xva; y = ya; }
    else                 { W = Wb; x = xvb; y = yb; }
    gemv_wave<0>(W, x, nullptr, y);
}

// ---------- Phase 2: two independent LN chains, one block each ----------
__global__ __launch_bounds__(1024) void phase2_kernel(
    const float* __restrict__ mv1, const float* __restrict__ mv2, const float* __restrict__ mv3,
    const float* __restrict__ bias_h1, const float* __restrict__ bias_h2,
    const float* __restrict__ g_h1, const float* __restrict__ bln_h1,
    const float* __restrict__ g_h2, const float* __restrict__ bln_h2,
    float* __restrict__ h1_p2, float* __restrict__ h2_p2)
{
    __shared__ float sbuf[32];
    const int t = threadIdx.x;
    if (blockIdx.x == 0) {
        float4 g = ld4(g_h1, t), b = ld4(bln_h1, t);
        float4 v = ld4(mv1, t);
        LNStat s1 = ln_stats(v, sbuf);
        float4 fb = ln_apply(v, s1, g, b);
        float4 tt = add4(add4(ld4(mv3, t), fb), ld4(bias_h1, t));
        LNStat s2 = ln_stats(tt, sbuf);
        st4(h1_p2, t, relu4(ln_apply(tt, s2, g, b)));
    } else {
        float4 g = ld4(g_h2, t), b = ld4(bln_h2, t);
        float4 v = ld4(mv2, t);
        LNStat s1 = ln_stats(v, sbuf);
        float4 fb = ln_apply(v, s1, g, b);
        float4 tt = add4(fb, ld4(bias_h2, t));
        LNStat s2 = ln_stats(tt, sbuf);
        st4(h2_p2, t, relu4(ln_apply(tt, s2, g, b)));
    }
}

// ---------- Phase 3 norms: two independent LNs, one block each ----------
__global__ __launch_bounds__(1024) void phase3_kernel(
    const float* __restrict__ mv4, const float* __restrict__ mv5,
    const float* __restrict__ bias_h1, const float* __restrict__ bias_h2,
    const float* __restrict__ g_h1, const float* __restrict__ bln_h1,
    const float* __restrict__ g_h2, const float* __restrict__ bln_h2,
    float* __restrict__ h1_f, float* __restrict__ h2_f)
{
    __shared__ float sbuf[32];
    const int t = threadIdx.x;
    const float* mv;  const float* bias; const float* g; const float* b; float* out;
    if (blockIdx.x == 0) { mv = mv4; bias = bias_h1; g = g_h1; b = bln_h1; out = h1_f; }
    else                 { mv = mv5; bias = bias_h2; g = g_h2; b = bln_h2; out = h2_f; }
    float4 v = add4(ld4(mv, t), ld4(bias, t));
    LNStat s = ln_stats(v, sbuf);
    st4(out, t, relu4(ln_apply(v, s, ld4(g, t), ld4(b, t))));
}

// ---------- Final: o = tanh(LN(bln_o + mv6 + mv7 + bias_o, g_o, bln_o)) ----------
__global__ __launch_bounds__(1024) void final_kernel(
    const float* __restrict__ mv6, const float* __restrict__ mv7,
    const float* __restrict__ bias_o, const float* __restrict__ bln_o,
    const float* __restrict__ g_o,
    float* __restrict__ out)
{
    __shared__ float sbuf[32];
    const int t = threadIdx.x;
    float4 v = add4(add4(ld4(bln_o, t), ld4(mv6, t)), add4(ld4(mv7, t), ld4(bias_o, t)));
    LNStat s = ln_stats(v, sbuf);
    float4 r = ln_apply(v, s, ld4(g_o, t), ld4(bln_o, t));
    st4(out, t, make_float4(tanhf(r.x), tanhf(r.y), tanhf(r.z), tanhf(r.w)));
}

// ---------- launch ----------

extern "C" void kernel_launch(void* const* d_in, const int* in_sizes, int n_in,
                              void* d_out, int out_size, void* d_ws, size_t ws_size,
                              hipStream_t stream) {
    const float* input_raw = (const float*)d_in[0];
    const float* h1_prev   = (const float*)d_in[1];
    const float* h2_prev   = (const float*)d_in[2];
    const float* W_I_H1    = (const float*)d_in[3];
    const float* W_H1_H1   = (const float*)d_in[4];
    const float* W_H1_H2   = (const float*)d_in[5];
    const float* W_H2_H1   = (const float*)d_in[6];
    const float* W_H2_H2   = (const float*)d_in[7];
    const float* W_H1_O    = (const float*)d_in[8];
    const float* W_H2_O    = (const float*)d_in[9];
    const float* bias_h1   = (const float*)d_in[10];
    const float* bias_h2   = (const float*)d_in[11];
    const float* bias_o    = (const float*)d_in[12];
    // d_in[13] = g_i (unused: LN(zeros) == beta)
    const float* b_i       = (const float*)d_in[14];
    const float* g_h1      = (const float*)d_in[15];
    const float* bln_h1    = (const float*)d_in[16];
    const float* g_h2      = (const float*)d_in[17];
    const float* bln_h2    = (const float*)d_in[18];
    const float* g_o       = (const float*)d_in[19];
    const float* bln_o     = (const float*)d_in[20];

    float* ws    = (float*)d_ws;
    float* mv1   = ws;
    float* mv2   = ws + 1 * NN;
    float* mv3   = ws + 2 * NN;
    float* h1_p2 = ws + 3 * NN;
    float* h2_p2 = ws + 4 * NN;
    float* mv4   = ws + 5 * NN;
    float* mv5   = ws + 6 * NN;
    float* h1_f  = ws + 7 * NN;
    float* h2_f  = ws + 8 * NN;
    float* mv6   = ws + 9 * NN;
    float* mv7   = ws + 10 * NN;

    // Stage A: 3 independent GEMVs (NT register-stream, moving window)
    gemv_stageA<<<dim3(GXW, 3), BLK, 0, stream>>>(
        W_H1_H1, h1_prev, W_H2_H2, h2_prev, W_I_H1, input_raw, b_i, mv1, mv2, mv3);

    // Phase 2 LN chains
    phase2_kernel<<<2, 1024, 0, stream>>>(
        mv1, mv2, mv3, bias_h1, bias_h2, g_h1, bln_h1, g_h2, bln_h2, h1_p2, h2_p2);

    // Stage B: mv4 = W_H2_H1 @ h2_p2 ; mv5 = W_H1_H2 @ h1_p2
    gemv_pair<<<dim3(GXW, 2), BLK, 0, stream>>>(
        W_H2_H1, h2_p2, mv4, W_H1_H2, h1_p2, mv5);

    // Phase 3 norms
    phase3_kernel<<<2, 1024, 0, stream>>>(
        mv4, mv5, bias_h1, bias_h2, g_h1, bln_h1, g_h2, bln_h2, h1_f, h2_f);

    // Stage C: mv6 = W_H1_O @ h1_f ; mv7 = W_H2_O @ h2_f
    gemv_pair<<<dim3(GXW, 2), BLK, 0, stream>>>(
        W_H1_O, h1_f, mv6, W_H2_O, h2_f, mv7);

    // Final output
    final_kernel<<<1, 1024, 0, stream>>>(
        mv6, mv7, bias_o, bln_o, g_o, (float*)d_out);
}

// Round 13
// 87.022 us; speedup vs baseline: 1.5985x; 1.0671x over previous
//
#include <hip/hip_runtime.h>
#include <math.h>

#define NN 4096
#define GX 256              // blocks per matrix; block b owns rows {b + j*GX}
#define NROWS 16
#define BLK 256

// ---------- small helpers ----------

__device__ __forceinline__ float4 ld4(const float* __restrict__ p, int t) {
    return reinterpret_cast<const float4*>(p)[t];
}
__device__ __forceinline__ void st4(float* __restrict__ p, int t, float4 v) {
    reinterpret_cast<float4*>(p)[t] = v;
}
__device__ __forceinline__ float4 add4(float4 a, float4 b) {
    return make_float4(a.x + b.x, a.y + b.y, a.z + b.z, a.w + b.w);
}

// async global->LDS, 16B per lane; LDS dst is wave-uniform base (+lane*16 implicit)
// AUX cache policy: 0 = normal (allocates in L2/LLC), 2 = NT (no retention).
typedef const __attribute__((address_space(1))) unsigned int* gas1_u32;
typedef __attribute__((address_space(3))) unsigned int* las3_u32;
template<int AUX>
__device__ __forceinline__ void async16(const float* g, float* l) {
    __builtin_amdgcn_global_load_lds((gas1_u32)(const void*)g, (las3_u32)(void*)l, 16, 0, AUX);
}

// stage one full 16 KB row into LDS: wave w covers bytes [4w,4w+4) KB
template<int AUX>
__device__ __forceinline__ void stage_row(const float* __restrict__ W, int row,
                                          float* __restrict__ buf, int wave, int lane) {
    const float* g = W + (size_t)row * NN + wave * 1024 + lane * 4;
    float* l = buf + wave * 1024;
    async16<AUX>(g,       l);
    async16<AUX>(g + 256, l + 256);
    async16<AUX>(g + 512, l + 512);
    async16<AUX>(g + 768, l + 768);
}

// policy dispatch: NT for row-steps j >= NT_FROM_J (block-uniform branch)
template<int NT_FROM_J>
__device__ __forceinline__ void stage_row_pol(const float* __restrict__ W, int j, int r0,
                                              float* __restrict__ buf, int wave, int lane) {
    if (j >= NT_FROM_J) stage_row<2>(W, r0 + j * GX, buf, wave, lane);
    else                stage_row<0>(W, r0 + j * GX, buf, wave, lane);
}

// dot(row-in-LDS, x-in-regs) -> wave-reduced partial (valid in lane 0)
__device__ __forceinline__ float dot_row(const float* __restrict__ buf,
                                         const float4 xr[4], int tid) {
    const float4* b4 = reinterpret_cast<const float4*>(buf);
    float p = 0.f;
    #pragma unroll
    for (int i = 0; i < 4; ++i) {
        float4 w = b4[i * 256 + tid];
        p = fmaf(w.x, xr[i].x, p);
        p = fmaf(w.y, xr[i].y, p);
        p = fmaf(w.z, xr[i].z, p);
        p = fmaf(w.w, xr[i].w, p);
    }
    #pragma unroll
    for (int off = 32; off > 0; off >>= 1) p += __shfl_down(p, off, 64);
    return p;
}

// block-wide (sum, sumsq) reduction, blockDim.x == 1024 (16 waves)
__device__ __forceinline__ float2 block_reduce2(float s, float ss, float* sbuf) {
    #pragma unroll
    for (int off = 32; off > 0; off >>= 1) {
        s  += __shfl_down(s,  off, 64);
        ss += __shfl_down(ss, off, 64);
    }
    const int wave = threadIdx.x >> 6;
    const int lane = threadIdx.x & 63;
    if (lane == 0) { sbuf[wave] = s; sbuf[16 + wave] = ss; }
    __syncthreads();
    float rs = 0.f, rss = 0.f;
    if (threadIdx.x < 16) { rs = sbuf[threadIdx.x]; rss = sbuf[16 + threadIdx.x]; }
    if (wave == 0) {
        #pragma unroll
        for (int off = 8; off > 0; off >>= 1) {
            rs  += __shfl_down(rs,  off, 64);
            rss += __shfl_down(rss, off, 64);
        }
        if (lane == 0) { sbuf[0] = rs; sbuf[1] = rss; }
    }
    __syncthreads();
    float2 r = make_float2(sbuf[0], sbuf[1]);
    __syncthreads();
    return r;
}

struct LNStat { float mu, rstd; };

__device__ __forceinline__ LNStat ln_stats(float4 v, float* sbuf) {
    float s  = v.x + v.y + v.z + v.w;
    float ss = v.x * v.x + v.y * v.y + v.z * v.z + v.w * v.w;
    float2 r = block_reduce2(s, ss, sbuf);
    LNStat o;
    o.mu = r.x * (1.0f / NN);
    float var = r.y * (1.0f / NN) - o.mu * o.mu;
    o.rstd = rsqrtf(var + 1e-5f);
    return o;
}

__device__ __forceinline__ float4 ln_apply(float4 v, LNStat st, float4 g, float4 b) {
    return make_float4((v.x - st.mu) * st.rstd * g.x + b.x,
                       (v.y - st.mu) * st.rstd * g.y + b.y,
                       (v.z - st.mu) * st.rstd * g.z + b.z,
                       (v.w - st.mu) * st.rstd * g.w + b.w);
}

__device__ __forceinline__ float4 relu4(float4 v) {
    return make_float4(fmaxf(v.x, 0.f), fmaxf(v.y, 0.f), fmaxf(v.z, 0.f), fmaxf(v.w, 0.f));
}

// ---------- GEMV core: moving-window sweep, row double-buffer (R9 structure) ----------
// Block b owns rows {b + j*GX}: at step j all blocks of a matrix read one
// contiguous 4 MB window. Stage row j+1 while computing row j from LDS against
// x in registers. NT_FROM_J selects the L3 partition: rows j < NT_FROM_J are
// read with normal (allocating) policy and stay LLC-resident across replays;
// rows j >= NT_FROM_J stream non-temporally.

template<int NT_FROM_J>
__device__ __forceinline__ void gemv_core(const float* __restrict__ W,
                                          const float* __restrict__ x,
                                          const float* __restrict__ xadd,
                                          float* __restrict__ y,
                                          float* t0, float* t1, float* sbuf) {
    const int tid  = threadIdx.x;
    const int wave = tid >> 6;
    const int lane = tid & 63;
    const int r0 = blockIdx.x;          // rows r0 + j*GX

    stage_row_pol<NT_FROM_J>(W, 0, r0, t0, wave, lane);

    float4 xr[4];
    const float4* x4 = reinterpret_cast<const float4*>(x);
    #pragma unroll
    for (int i = 0; i < 4; ++i) xr[i] = x4[i * 256 + tid];
    if (xadd) {
        const float4* a4 = reinterpret_cast<const float4*>(xadd);
        #pragma unroll
        for (int i = 0; i < 4; ++i) xr[i] = add4(xr[i], a4[i * 256 + tid]);
    }
    __syncthreads();   // t0 staged (vmcnt drain), xr loaded

    #pragma unroll 1
    for (int j = 0; j < NROWS; j += 2) {
        if (tid == 0 && j > 0) y[r0 + (j - 1) * GX] = sbuf[4] + sbuf[5] + sbuf[6] + sbuf[7];
        if (j + 1 < NROWS) stage_row_pol<NT_FROM_J>(W, j + 1, r0, t1, wave, lane);
        {
            float p = dot_row(t0, xr, tid);
            if (lane == 0) sbuf[wave] = p;
        }
        __syncthreads();
        if (tid == 0) y[r0 + j * GX] = sbuf[0] + sbuf[1] + sbuf[2] + sbuf[3];
        if (j + 2 < NROWS) stage_row_pol<NT_FROM_J>(W, j + 2, r0, t0, wave, lane);
        {
            float p = dot_row(t1, xr, tid);
            if (lane == 0) sbuf[4 + wave] = p;
        }
        __syncthreads();
    }
    if (tid == 0) y[r0 + (NROWS - 1) * GX] = sbuf[4] + sbuf[5] + sbuf[6] + sbuf[7];
}

// Stage A: mv1 = W_H1_H1 @ h1_prev; mv2 = W_H2_H2 @ h2_prev; mv3 = W_I_H1 @ (input_raw + b_i)
// Partition: first 10/16 of W_H1_H1 (40 MiB) kept LLC-resident; all else NT.
__global__ __launch_bounds__(BLK) void gemv_stageA(
    const float* __restrict__ W_H1_H1, const float* __restrict__ h1_prev,
    const float* __restrict__ W_H2_H2, const float* __restrict__ h2_prev,
    const float* __restrict__ W_I_H1,  const float* __restrict__ input_raw,
    const float* __restrict__ b_i,
    float* __restrict__ mv1, float* __restrict__ mv2, float* __restrict__ mv3)
{
    __shared__ float t0[NN], t1[NN];   // 16 KB each (one row)
    __shared__ float sbuf[8];
    if (blockIdx.y == 0)
        gemv_core<10>(W_H1_H1, h1_prev, nullptr, mv1, t0, t1, sbuf);   // j<10 cached
    else if (blockIdx.y == 1)
        gemv_core<0>(W_H2_H2, h2_prev, nullptr, mv2, t0, t1, sbuf);    // full NT
    else
        gemv_core<0>(W_I_H1, input_raw, b_i, mv3, t0, t1, sbuf);       // full NT
}

// Pair of independent GEMVs (stages B and C).
// Last 3/16 of each matrix (12 MiB x 4 = 48 MiB) streams NT from HBM,
// overlapping with L3-fed compute of the rest; 208 MiB stays LLC-resident.
__global__ __launch_bounds__(BLK) void gemv_pair(
    const float* __restrict__ Wa, const float* __restrict__ xa, float* __restrict__ ya,
    const float* __restrict__ Wb, const float* __restrict__ xb, float* __restrict__ yb)
{
    __shared__ float t0[NN], t1[NN];
    __shared__ float sbuf[8];
    if (blockIdx.y == 0) gemv_core<13>(Wa, xa, nullptr, ya, t0, t1, sbuf);
    else                 gemv_core<13>(Wb, xb, nullptr, yb, t0, t1, sbuf);
}

// ---------- Phase 2: two independent LN chains, one block each ----------
__global__ __launch_bounds__(1024) void phase2_kernel(
    const float* __restrict__ mv1, const float* __restrict__ mv2, const float* __restrict__ mv3,
    const float* __restrict__ bias_h1, const float* __restrict__ bias_h2,
    const float* __restrict__ g_h1, const float* __restrict__ bln_h1,
    const float* __restrict__ g_h2, const float* __restrict__ bln_h2,
    float* __restrict__ h1_p2, float* __restrict__ h2_p2)
{
    __shared__ float sbuf[32];
    const int t = threadIdx.x;
    if (blockIdx.x == 0) {
        float4 g = ld4(g_h1, t), b = ld4(bln_h1, t);
        float4 v = ld4(mv1, t);
        LNStat s1 = ln_stats(v, sbuf);
        float4 fb = ln_apply(v, s1, g, b);
        float4 tt = add4(add4(ld4(mv3, t), fb), ld4(bias_h1, t));
        LNStat s2 = ln_stats(tt, sbuf);
        st4(h1_p2, t, relu4(ln_apply(tt, s2, g, b)));
    } else {
        float4 g = ld4(g_h2, t), b = ld4(bln_h2, t);
        float4 v = ld4(mv2, t);
        LNStat s1 = ln_stats(v, sbuf);
        float4 fb = ln_apply(v, s1, g, b);
        float4 tt = add4(fb, ld4(bias_h2, t));
        LNStat s2 = ln_stats(tt, sbuf);
        st4(h2_p2, t, relu4(ln_apply(tt, s2, g, b)));
    }
}

// ---------- Phase 3 norms: two independent LNs, one block each ----------
__global__ __launch_bounds__(1024) void phase3_kernel(
    const float* __restrict__ mv4, const float* __restrict__ mv5,
    const float* __restrict__ bias_h1, const float* __restrict__ bias_h2,
    const float* __restrict__ g_h1, const float* __restrict__ bln_h1,
    const float* __restrict__ g_h2, const float* __restrict__ bln_h2,
    float* __restrict__ h1_f, float* __restrict__ h2_f)
{
    __shared__ float sbuf[32];
    const int t = threadIdx.x;
    const float* mv;  const float* bias; const float* g; const float* b; float* out;
    if (blockIdx.x == 0) { mv = mv4; bias = bias_h1; g = g_h1; b = bln_h1; out = h1_f; }
    else                 { mv = mv5; bias = bias_h2; g = g_h2; b = bln_h2; out = h2_f; }
    float4 v = add4(ld4(mv, t), ld4(bias, t));
    LNStat s = ln_stats(v, sbuf);
    st4(out, t, relu4(ln_apply(v, s, ld4(g, t), ld4(b, t))));
}

// ---------- Final: o = tanh(LN(bln_o + mv6 + mv7 + bias_o, g_o, bln_o)) ----------
__global__ __launch_bounds__(1024) void final_kernel(
    const float* __restrict__ mv6, const float* __restrict__ mv7,
    const float* __restrict__ bias_o, const float* __restrict__ bln_o,
    const float* __restrict__ g_o,
    float* __restrict__ out)
{
    __shared__ float sbuf[32];
    const int t = threadIdx.x;
    float4 v = add4(add4(ld4(bln_o, t), ld4(mv6, t)), add4(ld4(mv7, t), ld4(bias_o, t)));
    LNStat s = ln_stats(v, sbuf);
    float4 r = ln_apply(v, s, ld4(g_o, t), ld4(bln_o, t));
    st4(out, t, make_float4(tanhf(r.x), tanhf(r.y), tanhf(r.z), tanhf(r.w)));
}

// ---------- launch ----------

extern "C" void kernel_launch(void* const* d_in, const int* in_sizes, int n_in,
                              void* d_out, int out_size, void* d_ws, size_t ws_size,
                              hipStream_t stream) {
    const float* input_raw = (const float*)d_in[0];
    const float* h1_prev   = (const float*)d_in[1];
    const float* h2_prev   = (const float*)d_in[2];
    const float* W_I_H1    = (const float*)d_in[3];
    const float* W_H1_H1   = (const float*)d_in[4];
    const float* W_H1_H2   = (const float*)d_in[5];
    const float* W_H2_H1   = (const float*)d_in[6];
    const float* W_H2_H2   = (const float*)d_in[7];
    const float* W_H1_O    = (const float*)d_in[8];
    const float* W_H2_O    = (const float*)d_in[9];
    const float* bias_h1   = (const float*)d_in[10];
    const float* bias_h2   = (const float*)d_in[11];
    const float* bias_o    = (const float*)d_in[12];
    // d_in[13] = g_i (unused: LN(zeros) == beta)
    const float* b_i       = (const float*)d_in[14];
    const float* g_h1      = (const float*)d_in[15];
    const float* bln_h1    = (const float*)d_in[16];
    const float* g_h2      = (const float*)d_in[17];
    const float* bln_h2    = (const float*)d_in[18];
    const float* g_o       = (const float*)d_in[19];
    const float* bln_o     = (const float*)d_in[20];

    float* ws    = (float*)d_ws;
    float* mv1   = ws;
    float* mv2   = ws + 1 * NN;
    float* mv3   = ws + 2 * NN;
    float* h1_p2 = ws + 3 * NN;
    float* h2_p2 = ws + 4 * NN;
    float* mv4   = ws + 5 * NN;
    float* mv5   = ws + 6 * NN;
    float* h1_f  = ws + 7 * NN;
    float* h2_f  = ws + 8 * NN;
    float* mv6   = ws + 9 * NN;
    float* mv7   = ws + 10 * NN;

    // Stage A: 3 independent GEMVs (partitioned NT streaming, moving window)
    gemv_stageA<<<dim3(GX, 3), BLK, 0, stream>>>(
        W_H1_H1, h1_prev, W_H2_H2, h2_prev, W_I_H1, input_raw, b_i, mv1, mv2, mv3);

    // Phase 2 LN chains
    phase2_kernel<<<2, 1024, 0, stream>>>(
        mv1, mv2, mv3, bias_h1, bias_h2, g_h1, bln_h1, g_h2, bln_h2, h1_p2, h2_p2);

    // Stage B: mv4 = W_H2_H1 @ h2_p2 ; mv5 = W_H1_H2 @ h1_p2
    gemv_pair<<<dim3(GX, 2), BLK, 0, stream>>>(
        W_H2_H1, h2_p2, mv4, W_H1_H2, h1_p2, mv5);

    // Phase 3 norms
    phase3_kernel<<<2, 1024, 0, stream>>>(
        mv4, mv5, bias_h1, bias_h2, g_h1, bln_h1, g_h2, bln_h2, h1_f, h2_f);

    // Stage C: mv6 = W_H1_O @ h1_f ; mv7 = W_H2_O @ h2_f
    gemv_pair<<<dim3(GX, 2), BLK, 0, stream>>>(
        W_H1_O, h1_f, mv6, W_H2_O, h2_f, mv7);

    // Final output
    final_kernel<<<1, 1024, 0, stream>>>(
        mv6, mv7, bias_o, bln_o, g_o, (float*)d_out);
}